// Round 1
// baseline (100.860 us; speedup 1.0000x reference)
//
#include <hip/hip_runtime.h>
#include <hip/hip_bf16.h>

typedef __attribute__((ext_vector_type(8))) short bf16x8;   // MFMA A/B frag (8 bf16)
typedef __attribute__((ext_vector_type(4))) float f32x4;    // MFMA C/D frag

constexpr int BM = 64;      // output rows (h) per block
constexpr int BN = 64;      // output cols (w) per block
constexpr int BK = 64;      // points per K-step
constexpr int NPTS = 4096;
constexpr int HH = 256;
constexpr int WW = 256;

// S = sqrt(INV_VAR * log2(e)); exp(-INV_VAR*d^2) = exp2(-(S*d)^2)
// INV_VAR = 1/(2*(1.5^2+1e-8)) = 0.2222222212345679
#define SCALE_S 0.56621453f

__device__ inline short f2bs(float x) {
    __hip_bfloat16 b = __float2bfloat16(x);   // RNE
    return __builtin_bit_cast(short, b);
}

__global__ __launch_bounds__(256, 2) void soft_raster_kernel(
    const float* __restrict__ p2d,   // (32, 4096, 2)
    const float* __restrict__ pz,    // (32, 4096)
    float* __restrict__ out)         // (32, 256, 256)
{
    const int bk  = blockIdx.z;
    const int tm  = blockIdx.y * BM;
    const int tn  = blockIdx.x * BN;
    const int tid = threadIdx.x;

    __shared__ __align__(16) unsigned short lwy[BM * BK];  // [m][k], XOR-swizzled
    __shared__ __align__(16) unsigned short lwx[BN * BK];  // [n][k], XOR-swizzled
    __shared__ float lys[BK];   // y * S
    __shared__ float lxs[BK];   // x * S
    __shared__ float lzi[BK];   // 1/max(z,1e-5)

    const int wid  = tid >> 6;          // wave 0..3 -> 2x2
    const int lane = tid & 63;
    const int wm   = (wid >> 1) << 5;   // wave row offset (0/32)
    const int wn   = (wid & 1) << 5;    // wave col offset (0/32)
    const int g    = lane >> 4;         // k-group 0..3
    const int r    = lane & 15;

    f32x4 acc[2][2] = {};

    const size_t pbase = (size_t)bk * NPTS;

    for (int k0 = 0; k0 < NPTS; k0 += BK) {
        __syncthreads();   // protect LDS from previous iteration's readers

        // ---- stage 64 points into LDS (pre-scaled) ----
        if (tid < BK) {
            float2 xy = reinterpret_cast<const float2*>(p2d)[pbase + k0 + tid];
            float  z  = pz[pbase + k0 + tid];
            lxs[tid] = xy.x * SCALE_S;
            lys[tid] = xy.y * SCALE_S;
            lzi[tid] = __builtin_amdgcn_rcpf(fmaxf(z, 1e-5f));
        }
        __syncthreads();

        // ---- generate Wy (64x64) and Wx (64x64) bf16 tiles into LDS ----
        // chunk = 8 consecutive-k bf16 for one coordinate q -> one 16B write
        #pragma unroll
        for (int half = 0; half < 2; ++half) {
            const float* coord      = (half == 0) ? lys : lxs;
            unsigned short* dst     = (half == 0) ? lwy : lwx;
            const int       cb      = (half == 0) ? tm  : tn;
            #pragma unroll
            for (int it = 0; it < 2; ++it) {
                const int cc = tid + (it << 8);       // 0..511
                const int q  = cc >> 3;               // coordinate within tile
                const int kg = cc & 7;                // k-group (8 points)
                const float qs = (float)(cb + q) * SCALE_S;
                float4 c0 = *reinterpret_cast<const float4*>(&coord[kg * 8]);
                float4 c1 = *reinterpret_cast<const float4*>(&coord[kg * 8 + 4]);
                float e0 = exp2f(-((qs - c0.x) * (qs - c0.x)));
                float e1 = exp2f(-((qs - c0.y) * (qs - c0.y)));
                float e2 = exp2f(-((qs - c0.z) * (qs - c0.z)));
                float e3 = exp2f(-((qs - c0.w) * (qs - c0.w)));
                float e4 = exp2f(-((qs - c1.x) * (qs - c1.x)));
                float e5 = exp2f(-((qs - c1.y) * (qs - c1.y)));
                float e6 = exp2f(-((qs - c1.z) * (qs - c1.z)));
                float e7 = exp2f(-((qs - c1.w) * (qs - c1.w)));
                if (half == 0) {   // fold inv_z into Wy
                    float4 z0 = *reinterpret_cast<const float4*>(&lzi[kg * 8]);
                    float4 z1 = *reinterpret_cast<const float4*>(&lzi[kg * 8 + 4]);
                    e0 *= z0.x; e1 *= z0.y; e2 *= z0.z; e3 *= z0.w;
                    e4 *= z1.x; e5 *= z1.y; e6 *= z1.z; e7 *= z1.w;
                }
                bf16x8 v;
                v[0] = f2bs(e0); v[1] = f2bs(e1); v[2] = f2bs(e2); v[3] = f2bs(e3);
                v[4] = f2bs(e4); v[5] = f2bs(e5); v[6] = f2bs(e6); v[7] = f2bs(e7);
                const int idx = ((q << 6) + (kg << 3)) ^ ((q & 7) << 3);  // swizzle
                *reinterpret_cast<bf16x8*>(&dst[idx]) = v;
            }
        }
        __syncthreads();

        // ---- MFMA: 2 K-substeps of 32, per-wave 2x2 fragments of 16x16 ----
        #pragma unroll
        for (int kk = 0; kk < 2; ++kk) {
            bf16x8 af[2], bfr[2];
            #pragma unroll
            for (int i = 0; i < 2; ++i) {
                const int qa = wm + (i << 4) + r;
                af[i] = *reinterpret_cast<const bf16x8*>(
                    &lwy[((qa << 6) + (kk << 5) + (g << 3)) ^ ((qa & 7) << 3)]);
                const int qb = wn + (i << 4) + r;
                bfr[i] = *reinterpret_cast<const bf16x8*>(
                    &lwx[((qb << 6) + (kk << 5) + (g << 3)) ^ ((qb & 7) << 3)]);
            }
            #pragma unroll
            for (int mi = 0; mi < 2; ++mi)
                #pragma unroll
                for (int ni = 0; ni < 2; ++ni)
                    acc[mi][ni] = __builtin_amdgcn_mfma_f32_16x16x32_bf16(
                        af[mi], bfr[ni], acc[mi][ni], 0, 0, 0);
        }
    }

    // ---- epilogue: C/D layout col=lane&15, row=4*(lane>>4)+reg ----
    float* obase = out + (size_t)bk * (HH * WW);
    #pragma unroll
    for (int mi = 0; mi < 2; ++mi) {
        #pragma unroll
        for (int ni = 0; ni < 2; ++ni) {
            const int col  = tn + wn + (ni << 4) + r;
            const int row0 = tm + wm + (mi << 4) + (g << 2);
            #pragma unroll
            for (int j = 0; j < 4; ++j)
                obase[(size_t)(row0 + j) * WW + col] = acc[mi][ni][j];
        }
    }
}

extern "C" void kernel_launch(void* const* d_in, const int* in_sizes, int n_in,
                              void* d_out, int out_size, void* d_ws, size_t ws_size,
                              hipStream_t stream) {
    const float* p2d = (const float*)d_in[0];
    const float* pz  = (const float*)d_in[1];
    float* out       = (float*)d_out;
    const int nbk    = in_sizes[1] / NPTS;   // B*K = 32
    dim3 grid(WW / BN, HH / BM, nbk);        // (4, 4, 32) = 512 WGs
    dim3 block(256);
    hipLaunchKernelGGL(soft_raster_kernel, grid, block, 0, stream, p2d, pz, out);
}

// Round 2
// 23.631 us; speedup vs baseline: 4.2681x; 4.2681x over previous
//
#include <hip/hip_runtime.h>
#include <hip/hip_bf16.h>

typedef __attribute__((ext_vector_type(8))) short bf16x8;   // MFMA A/B frag (8 bf16)
typedef __attribute__((ext_vector_type(4))) float f32x4;    // MFMA C/D frag

constexpr int BM = 64;      // output rows (h) per block
constexpr int BN = 64;      // output cols (w) per block
constexpr int BK = 64;      // points per K-step
constexpr int NPTS = 4096;
constexpr int HH = 256;
constexpr int WW = 256;
constexpr int CAP = 2048;   // max compacted points per tile (mean ~414)

// S = sqrt(INV_VAR * log2(e)); exp(-INV_VAR*d^2) = exp2(-(S*d)^2)
#define SCALE_S 0.56621453f
// cutoff distance: dropped-point contribution <= 1e5*exp(-0.2222*100) = 2.2e-5
#define DCUT 10.0f

__device__ inline short f2bs(float x) {
    __hip_bfloat16 b = __float2bfloat16(x);   // RNE
    return __builtin_bit_cast(short, b);
}

__global__ __launch_bounds__(256, 2) void soft_raster_kernel(
    const float* __restrict__ p2d,   // (32, 4096, 2)
    const float* __restrict__ pz,    // (32, 4096)
    float* __restrict__ out)         // (32, 256, 256)
{
    const int bk  = blockIdx.z;
    const int tm  = blockIdx.y * BM;
    const int tn  = blockIdx.x * BN;
    const int tid = threadIdx.x;

    __shared__ __align__(16) unsigned short lwy[BM * BK];  // [m][k], XOR-swizzled
    __shared__ __align__(16) unsigned short lwx[BN * BK];  // [n][k], XOR-swizzled
    __shared__ unsigned short lidx[CAP];                   // compacted point ids
    __shared__ int scnt[4];
    __shared__ float lys[BK];   // y * S
    __shared__ float lxs[BK];   // x * S
    __shared__ float lzi[BK];   // 1/max(z,1e-5), 0 for tail padding

    const int wid  = tid >> 6;          // wave 0..3 -> 2x2
    const int lane = tid & 63;
    const int wm   = (wid >> 1) << 5;   // wave row offset (0/32)
    const int wn   = (wid & 1) << 5;    // wave col offset (0/32)
    const int g    = lane >> 4;         // k-group 0..3
    const int r    = lane & 15;

    const size_t pbase = (size_t)bk * NPTS;
    const float2* __restrict__ pxy = reinterpret_cast<const float2*>(p2d) + pbase;

    // ---- deterministic ordered compaction of in-window points ----
    const float xlo = (float)tn - DCUT, xhi = (float)(tn + BN - 1) + DCUT;
    const float ylo = (float)tm - DCUT, yhi = (float)(tm + BM - 1) + DCUT;

    // pass A: per-wave counts (wave w owns k in [w*1024, w*1024+1024))
    int mycnt = 0;
    #pragma unroll 4
    for (int it = 0; it < 16; ++it) {
        const int k = (wid << 10) + (it << 6) + lane;
        float2 xy = pxy[k];
        bool in = (xy.x > xlo) && (xy.x < xhi) && (xy.y > ylo) && (xy.y < yhi);
        mycnt += __popcll(__ballot(in));
    }
    if (lane == 0) scnt[wid] = mycnt;
    __syncthreads();

    int base = 0;
    #pragma unroll
    for (int w = 0; w < 4; ++w) base += (w < wid) ? scnt[w] : 0;
    const int total = scnt[0] + scnt[1] + scnt[2] + scnt[3];

    // pass B: ordered write of compacted indices
    #pragma unroll 4
    for (int it = 0; it < 16; ++it) {
        const int k = (wid << 10) + (it << 6) + lane;
        float2 xy = pxy[k];
        bool in = (xy.x > xlo) && (xy.x < xhi) && (xy.y > ylo) && (xy.y < yhi);
        unsigned long long b = __ballot(in);
        int pos = __popcll(b & ((1ull << lane) - 1ull));
        if (in && (base + pos) < CAP) lidx[base + pos] = (unsigned short)k;
        base += __popcll(b);
    }
    __syncthreads();

    f32x4 acc[2][2] = {};

    for (int k0 = 0; k0 < total; k0 += BK) {
        __syncthreads();   // protect LDS point arrays from previous readers

        // ---- gather up to 64 compacted points into LDS (pre-scaled) ----
        if (tid < BK) {
            const int j = k0 + tid;
            float xs = 0.f, ys = 0.f, zi = 0.f;   // tail: weight-0 points
            if (j < total) {
                const int kk = lidx[j];
                float2 xy = pxy[kk];
                float  z  = pz[pbase + kk];
                xs = xy.x * SCALE_S;
                ys = xy.y * SCALE_S;
                zi = __builtin_amdgcn_rcpf(fmaxf(z, 1e-5f));
            }
            lxs[tid] = xs; lys[tid] = ys; lzi[tid] = zi;
        }
        __syncthreads();

        // ---- generate Wy (64x64) and Wx (64x64) bf16 tiles into LDS ----
        #pragma unroll
        for (int half = 0; half < 2; ++half) {
            const float* coord      = (half == 0) ? lys : lxs;
            unsigned short* dst     = (half == 0) ? lwy : lwx;
            const int       cb      = (half == 0) ? tm  : tn;
            #pragma unroll
            for (int it = 0; it < 2; ++it) {
                const int cc = tid + (it << 8);       // 0..511
                const int q  = cc >> 3;               // coordinate within tile
                const int kg = cc & 7;                // k-group (8 points)
                const float qs = (float)(cb + q) * SCALE_S;
                float4 c0 = *reinterpret_cast<const float4*>(&coord[kg * 8]);
                float4 c1 = *reinterpret_cast<const float4*>(&coord[kg * 8 + 4]);
                float e0 = exp2f(-((qs - c0.x) * (qs - c0.x)));
                float e1 = exp2f(-((qs - c0.y) * (qs - c0.y)));
                float e2 = exp2f(-((qs - c0.z) * (qs - c0.z)));
                float e3 = exp2f(-((qs - c0.w) * (qs - c0.w)));
                float e4 = exp2f(-((qs - c1.x) * (qs - c1.x)));
                float e5 = exp2f(-((qs - c1.y) * (qs - c1.y)));
                float e6 = exp2f(-((qs - c1.z) * (qs - c1.z)));
                float e7 = exp2f(-((qs - c1.w) * (qs - c1.w)));
                if (half == 0) {   // fold inv_z into Wy
                    float4 z0 = *reinterpret_cast<const float4*>(&lzi[kg * 8]);
                    float4 z1 = *reinterpret_cast<const float4*>(&lzi[kg * 8 + 4]);
                    e0 *= z0.x; e1 *= z0.y; e2 *= z0.z; e3 *= z0.w;
                    e4 *= z1.x; e5 *= z1.y; e6 *= z1.z; e7 *= z1.w;
                }
                bf16x8 v;
                v[0] = f2bs(e0); v[1] = f2bs(e1); v[2] = f2bs(e2); v[3] = f2bs(e3);
                v[4] = f2bs(e4); v[5] = f2bs(e5); v[6] = f2bs(e6); v[7] = f2bs(e7);
                const int idx = ((q << 6) + (kg << 3)) ^ ((q & 7) << 3);  // swizzle
                *reinterpret_cast<bf16x8*>(&dst[idx]) = v;
            }
        }
        __syncthreads();

        // ---- MFMA: 2 K-substeps of 32, per-wave 2x2 fragments of 16x16 ----
        #pragma unroll
        for (int kk = 0; kk < 2; ++kk) {
            bf16x8 af[2], bfr[2];
            #pragma unroll
            for (int i = 0; i < 2; ++i) {
                const int qa = wm + (i << 4) + r;
                af[i] = *reinterpret_cast<const bf16x8*>(
                    &lwy[((qa << 6) + (kk << 5) + (g << 3)) ^ ((qa & 7) << 3)]);
                const int qb = wn + (i << 4) + r;
                bfr[i] = *reinterpret_cast<const bf16x8*>(
                    &lwx[((qb << 6) + (kk << 5) + (g << 3)) ^ ((qb & 7) << 3)]);
            }
            #pragma unroll
            for (int mi = 0; mi < 2; ++mi)
                #pragma unroll
                for (int ni = 0; ni < 2; ++ni)
                    acc[mi][ni] = __builtin_amdgcn_mfma_f32_16x16x32_bf16(
                        af[mi], bfr[ni], acc[mi][ni], 0, 0, 0);
        }
    }

    // ---- epilogue: C/D layout col=lane&15, row=4*(lane>>4)+reg ----
    float* obase = out + (size_t)bk * (HH * WW);
    #pragma unroll
    for (int mi = 0; mi < 2; ++mi) {
        #pragma unroll
        for (int ni = 0; ni < 2; ++ni) {
            const int col  = tn + wn + (ni << 4) + r;
            const int row0 = tm + wm + (mi << 4) + (g << 2);
            #pragma unroll
            for (int j = 0; j < 4; ++j)
                obase[(size_t)(row0 + j) * WW + col] = acc[mi][ni][j];
        }
    }
}

extern "C" void kernel_launch(void* const* d_in, const int* in_sizes, int n_in,
                              void* d_out, int out_size, void* d_ws, size_t ws_size,
                              hipStream_t stream) {
    const float* p2d = (const float*)d_in[0];
    const float* pz  = (const float*)d_in[1];
    float* out       = (float*)d_out;
    const int nbk    = in_sizes[1] / NPTS;   // B*K = 32
    dim3 grid(WW / BN, HH / BM, nbk);        // (4, 4, 32) = 512 WGs
    dim3 block(256);
    hipLaunchKernelGGL(soft_raster_kernel, grid, block, 0, stream, p2d, pz, out);
}